// Round 5
// baseline (95.147 us; speedup 1.0000x reference)
//
#include <hip/hip_runtime.h>
#include <hip/hip_fp16.h>
#include <math.h>

#define E_NUMC 100000
#define DIMC 32
#define NEIGHC 16
#define RULESC 8

struct __align__(16) h2x4 { __half2 x, y, z, w; };
struct __align__(8)  h2x2 { __half2 x, y; };

// Ws column-chunk swizzle: spreads the {o, o+8, o+16, o+24} read group
// across distinct banks. Chunk-granular -> keeps 16B alignment.
#define WCH(o, dc) ((dc) ^ ((((o) >> 3) & 3) << 1))

// ---------------------------------------------------------------------------
// Pre-pass: renormed fp16 embedding table in d_ws. 16 lanes per row.
// ---------------------------------------------------------------------------
__global__ __launch_bounds__(256) void renorm_f16_kernel(
    const float* __restrict__ emb, __half2* __restrict__ o16)
{
    const int row = blockIdx.x * 16 + (threadIdx.x >> 4);
    const int j = threadIdx.x & 15;
    const float2 f = ((const float2*)(emb + (long)row * DIMC))[j];
    float sq = f.x * f.x + f.y * f.y;
    sq += __shfl_xor(sq, 1, 64);
    sq += __shfl_xor(sq, 2, 64);
    sq += __shfl_xor(sq, 4, 64);
    sq += __shfl_xor(sq, 8, 64);
    const float s = fminf(1.0f, 1.0f / fmaxf(sqrtf(sq), 1e-7f));
    o16[(long)row * (DIMC / 2) + j] = __floats2half2_rn(f.x * s, f.y * s);
}

// ---------------------------------------------------------------------------
// Kernel 1: one (batch, rule) tree per 256-thread block.
// LDS layout: X[17][68] fp32: rows 0..15 = [h1 vec | mean2 vec] (d 0..63),
// row 16 = [user vec | mean1]. Ws[32][68] = W row-major (chunk-swizzled).
// Phase D fused with D2: thread (o = t&31, np = t>>5) computes output o for
// nodes {2np, 2np+1} (+ node 16 if np==7), all operands via ds_read_b128.
// ---------------------------------------------------------------------------
__global__ __launch_bounds__(256) void rgrec_tree16_kernel(
    const int* __restrict__ users, const int* __restrict__ rules,
    const int* __restrict__ adj, const __half2* __restrict__ emb16,
    const float* __restrict__ W, const float* __restrict__ bvec,
    float* __restrict__ res)
{
    const int b = blockIdx.x;
    const int r = blockIdx.y;
    const int t = threadIdx.x;
    const int lane = t & 63;

    __shared__ float X[17][68];   // [h1|mean2] rows, row16 = [u|mean1]
    __shared__ float Ws[32][68];  // W[o][d], chunk-swizzled columns
    __shared__ float v1s[16][33]; // level-0 outputs
    __shared__ float xe[68];      // [v0 | meanv1]
    __shared__ float bs[32];

    const int user = users[b];
    const int rid0 = rules[r * 2 + 0];
    const int rid1 = rules[r * 2 + 1];

    // longest dependency chain first: hop1 ids (per-wave, no barrier)
    int h1v = 0;
    if (lane < 16) h1v = adj[(rid0 * E_NUMC + user) * NEIGHC + lane];

    // ---- phase B ids: node m, child j ----
    const int m = t >> 4;
    const int j = t & 15;
    const int e1 = __shfl(h1v, m, 64);
    const int e2 = adj[(rid1 * E_NUMC + e1) * NEIGHC + j];

    // ---- phase C loads issued early: 17 rows, 8 B/lane ----
    const int g = t >> 3, k8 = t & 7;
    const bool cact = (t < 136);
    h2x2 craw;
    if (cact) {
        const int ec = (g < 16) ? __shfl(h1v, g, 64) : user;
        craw = ((const h2x2*)(emb16 + (long)ec * (DIMC / 2)))[k8];
    }

    // stage W: ds_write_b128, swizzled chunks
    {
        const float4* W4 = (const float4*)W;
        for (int i = t; i < 512; i += 256) {
            const float4 f = W4[i];
            const int o = i >> 4, c = i & 15;
            *(float4*)&Ws[o][4 * WCH(o, c)] = f;
        }
    }
    if (t < 32) bs[t] = bvec[t];

    // ---- phase B: dwordx4 gather + fp32 accumulate + 2-step butterfly ----
    {
        const int k = j & 3;        // 16-B chunk: dims 8k..8k+7
        const int h = j >> 2;       // row subset
        const int gbase = t & 48;   // wave-local base lane of this node group
        float acc[8];
#pragma unroll
        for (int d = 0; d < 8; ++d) acc[d] = 0.0f;
#pragma unroll
        for (int i = 0; i < 4; ++i) {
            const int ec = __shfl(e2, gbase + h + 4 * i, 64);
            const h2x4 raw = ((const h2x4*)(emb16 + (long)ec * (DIMC / 2)))[k];
            const float2 f0 = __half22float2(raw.x);
            const float2 f1 = __half22float2(raw.y);
            const float2 f2 = __half22float2(raw.z);
            const float2 f3 = __half22float2(raw.w);
            acc[0] += f0.x; acc[1] += f0.y;
            acc[2] += f1.x; acc[3] += f1.y;
            acc[4] += f2.x; acc[5] += f2.y;
            acc[6] += f3.x; acc[7] += f3.y;
        }
#pragma unroll
        for (int d = 0; d < 8; ++d) acc[d] += __shfl_xor(acc[d], 4, 64);
#pragma unroll
        for (int d = 0; d < 8; ++d) acc[d] += __shfl_xor(acc[d], 8, 64);
        *(float2*)&X[m][32 + 8 * k + 2 * h] =
            make_float2(acc[2 * h] * (1.0f / 16.0f),
                        acc[2 * h + 1] * (1.0f / 16.0f));
    }

    // ---- phase C: convert + store hop1/user rows (b128 writes) ----
    if (cact) {
        const float2 fa = __half22float2(craw.x);
        const float2 fb = __half22float2(craw.y);
        *(float4*)&X[g][4 * k8] = make_float4(fa.x, fa.y, fb.x, fb.y);
    }
    __syncthreads();   // barrier 1: X rows 0..16 (d<32), mean2 halves ready

    // ---- mean1 -> X[16][32..63] ----
    if (t < 32) {
        float mn = 0.0f;
#pragma unroll
        for (int m2 = 0; m2 < 16; ++m2) mn += X[m2][t];
        X[16][32 + t] = mn * (1.0f / 16.0f);
    }
    __syncthreads();   // barrier 2

    // ---- phase D (+D2 fused): b128 operands ----
    {
        const int o = t & 31, np = t >> 5;
        const int n0 = 2 * np, n1 = 2 * np + 1;
        float a0 = bs[o], a1 = a0, a2 = a0;
#pragma unroll
        for (int dc = 0; dc < 16; ++dc) {
            const float4 w = *(const float4*)&Ws[o][4 * WCH(o, dc)];
            const float4 x0 = *(const float4*)&X[n0][4 * dc];
            const float4 x1 = *(const float4*)&X[n1][4 * dc];
            a0 += w.x * x0.x + w.y * x0.y + w.z * x0.z + w.w * x0.w;
            a1 += w.x * x1.x + w.y * x1.y + w.z * x1.z + w.w * x1.w;
            if (np == 7) {
                const float4 x2 = *(const float4*)&X[16][4 * dc];
                a2 += w.x * x2.x + w.y * x2.y + w.z * x2.z + w.w * x2.w;
            }
        }
        v1s[n0][o] = fmaxf(a0, 0.0f);
        v1s[n1][o] = fmaxf(a1, 0.0f);
        if (np == 7) xe[o] = fmaxf(a2, 0.0f);   // v0
    }
    __syncthreads();   // barrier 3

    // ---- meanv1 -> xe[32..63] ----
    if (t < 32) {
        float mv = 0.0f;
#pragma unroll
        for (int m2 = 0; m2 < 16; ++m2) mv += v1s[m2][t];
        xe[32 + t] = mv * (1.0f / 16.0f);
    }
    __syncthreads();   // barrier 4

    // ---- phase E: 32-lane tail, b128 operands ----
    if (t < 32) {
        float a = bs[t];
#pragma unroll
        for (int dc = 0; dc < 16; ++dc) {
            const float4 w = *(const float4*)&Ws[t][4 * WCH(t, dc)];
            const float4 x = *(const float4*)&xe[4 * dc];
            a += w.x * x.x + w.y * x.y + w.z * x.z + w.w * x.w;
        }
        res[(b * RULESC + r) * DIMC + t] = tanhf(a);
    }
}

// ---------------------------------------------------------------------------
// Kernel 2: one wave per batch element — rule-weighted sum + item dot+sigmoid
// ---------------------------------------------------------------------------
__global__ __launch_bounds__(256) void rgrec_combine_kernel(
    const int* __restrict__ items, const float* __restrict__ emb,
    const float* __restrict__ rule_w, const float* __restrict__ res,
    float* __restrict__ out, int B)
{
    const int gw = (blockIdx.x * 256 + threadIdx.x) >> 6;
    const int lane = threadIdx.x & 63;
    if (gw >= B) return;
    const int b = gw;

    float ss = 0.0f;
#pragma unroll
    for (int i = 0; i < RULESC; ++i) { const float w = rule_w[i]; ss += w * w; }
    const float rws = fminf(1.0f, 1.0f / fmaxf(sqrtf(ss), 1e-7f));

    const int d = lane & 31, rh = lane >> 5;
    float acc = 0.0f;
#pragma unroll
    for (int rr = 0; rr < 4; ++rr) {
        const int r = rh * 4 + rr;
        acc += rule_w[r] * res[(b * RULESC + r) * DIMC + d];
    }
    acc += __shfl_xor(acc, 32, 64);
    acc *= rws;

    const int it = items[b];
    const float x = emb[(long)it * DIMC + d];
    float sq = x * x;
    sq += __shfl_xor(sq, 1, 64);
    sq += __shfl_xor(sq, 2, 64);
    sq += __shfl_xor(sq, 4, 64);
    sq += __shfl_xor(sq, 8, 64);
    sq += __shfl_xor(sq, 16, 64);
    const float s = fminf(1.0f, 1.0f / fmaxf(sqrtf(sq), 1e-7f));
    float p = acc * x * s;
    p += __shfl_xor(p, 1, 64);
    p += __shfl_xor(p, 2, 64);
    p += __shfl_xor(p, 4, 64);
    p += __shfl_xor(p, 8, 64);
    p += __shfl_xor(p, 16, 64);
    if (lane == 0) out[b] = 1.0f / (1.0f + expf(-p));
}

// ---------------------------------------------------------------------------
// Fallback fused fp32 kernel (known-good) if d_ws is too small.
// ---------------------------------------------------------------------------
__global__ __launch_bounds__(256) void rgrec_fused_kernel(
    const int* __restrict__ users, const int* __restrict__ items,
    const int* __restrict__ rules, const int* __restrict__ adj,
    const float* __restrict__ emb, const float* __restrict__ rule_w,
    const float* __restrict__ W, const float* __restrict__ bvec,
    float* __restrict__ out)
{
    const int b = blockIdx.x;
    const int t = threadIdx.x;

    __shared__ float Wt[64][33];
    __shared__ float bs[32];
    __shared__ float h1s[16][33];
    __shared__ float mean2[16][33];
    __shared__ float v1[16][33];
    __shared__ float u_vec[32];
    __shared__ float mean1[32];
    __shared__ float v0[32];
    __shared__ float meanv1[32];
    __shared__ float useru[32];
    __shared__ int   h1id[16];

    for (int i = t; i < 64 * 32; i += 256) {
        const int o = i >> 6, d = i & 63;
        Wt[d][o] = W[i];
    }
    if (t < 32) { bs[t] = bvec[t]; useru[t] = 0.0f; }

    float ss = 0.0f;
#pragma unroll
    for (int i = 0; i < RULESC; ++i) { const float w = rule_w[i]; ss += w * w; }
    const float rws = fminf(1.0f, 1.0f / fmaxf(sqrtf(ss), 1e-7f));

    const int user = users[b];

    for (int r = 0; r < RULESC; ++r) {
        const int rid0 = rules[r * 2 + 0];
        const int rid1 = rules[r * 2 + 1];
        if (t < 16) h1id[t] = adj[(rid0 * E_NUMC + user) * NEIGHC + t];
        __syncthreads();
        {
            const int m = t >> 4, j = t & 15;
            const int e1 = h1id[m];
            const int e2 = adj[(rid1 * E_NUMC + e1) * NEIGHC + j];
            float v[32];
            const float4* p = (const float4*)(emb + (long)e2 * DIMC);
            float sq = 0.0f;
#pragma unroll
            for (int q = 0; q < 8; ++q) {
                const float4 f = p[q];
                v[q * 4 + 0] = f.x; v[q * 4 + 1] = f.y;
                v[q * 4 + 2] = f.z; v[q * 4 + 3] = f.w;
                sq += f.x * f.x + f.y * f.y + f.z * f.z + f.w * f.w;
            }
            const float s =
                fminf(1.0f, 1.0f / fmaxf(sqrtf(sq), 1e-7f)) * (1.0f / 16.0f);
#pragma unroll
            for (int d = 0; d < 32; ++d) v[d] *= s;
#pragma unroll
            for (int st = 1; st < 16; st <<= 1) {
#pragma unroll
                for (int d = 0; d < 32; ++d) v[d] += __shfl_xor(v[d], st, 64);
            }
            mean2[m][j]      = v[j];
            mean2[m][j + 16] = v[j + 16];
        }
        if (t < 136) {
            const int g = t >> 3, k = t & 7;
            const int e = (g < 16) ? h1id[g] : user;
            const float4 f = ((const float4*)(emb + (long)e * DIMC))[k];
            float sq = f.x * f.x + f.y * f.y + f.z * f.z + f.w * f.w;
            sq += __shfl_xor(sq, 1, 64);
            sq += __shfl_xor(sq, 2, 64);
            sq += __shfl_xor(sq, 4, 64);
            const float s = fminf(1.0f, 1.0f / fmaxf(sqrtf(sq), 1e-7f));
            if (g < 16) {
                h1s[g][k * 4 + 0] = f.x * s; h1s[g][k * 4 + 1] = f.y * s;
                h1s[g][k * 4 + 2] = f.z * s; h1s[g][k * 4 + 3] = f.w * s;
            } else {
                u_vec[k * 4 + 0] = f.x * s; u_vec[k * 4 + 1] = f.y * s;
                u_vec[k * 4 + 2] = f.z * s; u_vec[k * 4 + 3] = f.w * s;
            }
        }
        __syncthreads();
        {
            const int m = t >> 4, o = t & 15;
            float a0 = bs[o], a1 = bs[o + 16];
#pragma unroll
            for (int d = 0; d < 32; ++d) {
                const float h = h1s[m][d];
                a0 += Wt[d][o] * h;
                a1 += Wt[d][o + 16] * h;
            }
#pragma unroll
            for (int d = 0; d < 32; ++d) {
                const float h = mean2[m][d];
                a0 += Wt[32 + d][o] * h;
                a1 += Wt[32 + d][o + 16] * h;
            }
            v1[m][o]      = fmaxf(a0, 0.0f);
            v1[m][o + 16] = fmaxf(a1, 0.0f);
        }
        if (t < 32) {
            float mn = 0.0f;
#pragma unroll
            for (int m2 = 0; m2 < 16; ++m2) mn += h1s[m2][t];
            mean1[t] = mn * (1.0f / 16.0f);
        }
        __syncthreads();
        if (t < 32) {
            float a = bs[t];
#pragma unroll
            for (int d = 0; d < 32; ++d) a += Wt[d][t] * u_vec[d];
#pragma unroll
            for (int d = 0; d < 32; ++d) a += Wt[32 + d][t] * mean1[d];
            v0[t] = fmaxf(a, 0.0f);
            float mv = 0.0f;
#pragma unroll
            for (int m2 = 0; m2 < 16; ++m2) mv += v1[m2][t];
            meanv1[t] = mv * (1.0f / 16.0f);
        }
        __syncthreads();
        if (t < 32) {
            float a = bs[t];
#pragma unroll
            for (int d = 0; d < 32; ++d) a += Wt[d][t] * v0[d];
#pragma unroll
            for (int d = 0; d < 32; ++d) a += Wt[32 + d][t] * meanv1[d];
            useru[t] += rule_w[r] * rws * tanhf(a);
        }
        __syncthreads();
    }

    if (t < 32) {
        const int it = items[b];
        const float x = emb[(long)it * DIMC + t];
        float sq = x * x;
        sq += __shfl_xor(sq, 1, 64);
        sq += __shfl_xor(sq, 2, 64);
        sq += __shfl_xor(sq, 4, 64);
        sq += __shfl_xor(sq, 8, 64);
        sq += __shfl_xor(sq, 16, 64);
        const float s = fminf(1.0f, 1.0f / fmaxf(sqrtf(sq), 1e-7f));
        float p = useru[t] * x * s;
        p += __shfl_xor(p, 1, 64);
        p += __shfl_xor(p, 2, 64);
        p += __shfl_xor(p, 4, 64);
        p += __shfl_xor(p, 8, 64);
        p += __shfl_xor(p, 16, 64);
        if (t == 0) out[b] = 1.0f / (1.0f + expf(-p));
    }
}

extern "C" void kernel_launch(void* const* d_in, const int* in_sizes, int n_in,
                              void* d_out, int out_size, void* d_ws, size_t ws_size,
                              hipStream_t stream) {
    const int*   users  = (const int*)d_in[0];
    const int*   items  = (const int*)d_in[1];
    const int*   rules  = (const int*)d_in[2];
    const int*   adj    = (const int*)d_in[3];
    const float* emb    = (const float*)d_in[4];
    const float* rule_w = (const float*)d_in[5];
    const float* W      = (const float*)d_in[6];
    const float* bvec   = (const float*)d_in[7];
    float*       out    = (float*)d_out;

    const int batch = in_sizes[0];  // 1024
    const size_t emb16_bytes = (size_t)E_NUMC * DIMC * sizeof(__half);  // 6.4 MB
    const size_t res_bytes   = (size_t)batch * RULESC * DIMC * sizeof(float);

    if (ws_size >= emb16_bytes + res_bytes) {
        __half2* emb16 = (__half2*)d_ws;
        float*   res   = (float*)((char*)d_ws + emb16_bytes);

        renorm_f16_kernel<<<dim3(E_NUMC / 16), dim3(256), 0, stream>>>(
            emb, emb16);
        rgrec_tree16_kernel<<<dim3(batch, RULESC), dim3(256), 0, stream>>>(
            users, rules, adj, emb16, W, bvec, res);
        const int nblk = (batch * 64 + 255) / 256;
        rgrec_combine_kernel<<<dim3(nblk), dim3(256), 0, stream>>>(
            items, emb, rule_w, res, out, batch);
    } else {
        rgrec_fused_kernel<<<dim3(batch), dim3(256), 0, stream>>>(
            users, items, rules, adj, emb, rule_w, W, bvec, out);
    }
}

// Round 6
// 55.250 us; speedup vs baseline: 1.7221x; 1.7221x over previous
//
#include <hip/hip_runtime.h>
#include <hip/hip_fp16.h>
#include <math.h>

#define E_NUMC 100000
#define DIMC 32
#define NEIGHC 16
#define RULESC 8

struct __align__(16) h2x4 { __half2 x, y, z, w; };
struct __align__(8)  h2x2 { __half2 x, y; };

// Ws column-chunk swizzle: spreads the {o, o+8, o+16, o+24} b128 read group
// across distinct banks. Chunk-granular -> keeps 16B alignment.
#define WCH(o, dc) ((dc) ^ ((((o) >> 3) & 3) << 1))

// ---------------------------------------------------------------------------
// Pre-pass: renormed fp16 embedding table in d_ws. 16 lanes per row.
// ---------------------------------------------------------------------------
__global__ __launch_bounds__(256) void renorm_f16_kernel(
    const float* __restrict__ emb, __half2* __restrict__ o16)
{
    const int row = blockIdx.x * 16 + (threadIdx.x >> 4);
    const int j = threadIdx.x & 15;
    const float2 f = ((const float2*)(emb + (long)row * DIMC))[j];
    float sq = f.x * f.x + f.y * f.y;
    sq += __shfl_xor(sq, 1, 64);
    sq += __shfl_xor(sq, 2, 64);
    sq += __shfl_xor(sq, 4, 64);
    sq += __shfl_xor(sq, 8, 64);
    const float s = fminf(1.0f, 1.0f / fmaxf(sqrtf(sq), 1e-7f));
    o16[(long)row * (DIMC / 2) + j] = __floats2half2_rn(f.x * s, f.y * s);
}

// ---------------------------------------------------------------------------
// Kernel 1: one (batch, rule) tree per 256-thread block. 2 barriers.
// LDS: X[17][68] (rows 0..15 = [h1 | mean2], row 16 = [u | mean1]),
//      Ws[32][68] = W row-major chunk-swizzled, vpart[4][33], xe[68], bs.
// D: thread (o=t&31, h=(t>>5)&1, w=t>>6) computes output o of nodes
//    {4w+2h, 4w+2h+1}; relu'd outputs accumulate into a register vsum
//    (v1 is never materialized - it only feeds meanv1).
// Final phase entirely in wave 0: v0 (pr=0) | meanv1 (pr=1), then E split
// across the two halves, combined with one shfl_xor.
// ---------------------------------------------------------------------------
__global__ __launch_bounds__(256, 6) void rgrec_tree16_kernel(
    const int* __restrict__ users, const int* __restrict__ rules,
    const int* __restrict__ adj, const __half2* __restrict__ emb16,
    const float* __restrict__ W, const float* __restrict__ bvec,
    float* __restrict__ res)
{
    const int b = blockIdx.x;
    const int r = blockIdx.y;
    const int t = threadIdx.x;
    const int lane = t & 63;

    __shared__ float X[17][68];
    __shared__ float Ws[32][68];
    __shared__ float vpart[4][33];
    __shared__ float xe[68];      // [v0 | meanv1]
    __shared__ float bs[32];

    const int user = users[b];
    const int rid0 = rules[r * 2 + 0];
    const int rid1 = rules[r * 2 + 1];

    // longest dependency chain first: hop1 ids (per-wave, no barrier)
    int h1v = 0;
    if (lane < 16) h1v = adj[(rid0 * E_NUMC + user) * NEIGHC + lane];

    // ---- phase B ids: node m, child j ----
    const int m = t >> 4;
    const int j = t & 15;
    const int e1 = __shfl(h1v, m, 64);
    const int e2 = adj[(rid1 * E_NUMC + e1) * NEIGHC + j];

    // ---- phase C loads issued early: 17 rows, 8 B/lane ----
    const int g = t >> 3, k8 = t & 7;
    const bool cact = (t < 136);
    h2x2 craw;
    if (cact) {
        const int ec = (g < 16) ? __shfl(h1v, g, 64) : user;
        craw = ((const h2x2*)(emb16 + (long)ec * (DIMC / 2)))[k8];
    }

    // stage W (b128 writes, swizzled chunks) + bias
    {
        const float4* W4 = (const float4*)W;
        for (int i = t; i < 512; i += 256) {
            const float4 f = W4[i];
            const int o = i >> 4, c = i & 15;
            *(float4*)&Ws[o][4 * WCH(o, c)] = f;
        }
    }
    if (t < 32) bs[t] = bvec[t];

    // ---- phase B: dwordx4 gather + fp32 accumulate + 2-step butterfly ----
    {
        const int k = j & 3;        // 16-B chunk: dims 8k..8k+7
        const int h = j >> 2;       // row subset
        const int gbase = t & 48;   // wave-local base lane of this node group
        float acc[8];
#pragma unroll
        for (int d = 0; d < 8; ++d) acc[d] = 0.0f;
#pragma unroll
        for (int i = 0; i < 4; ++i) {
            const int ec = __shfl(e2, gbase + h + 4 * i, 64);
            const h2x4 raw = ((const h2x4*)(emb16 + (long)ec * (DIMC / 2)))[k];
            const float2 f0 = __half22float2(raw.x);
            const float2 f1 = __half22float2(raw.y);
            const float2 f2 = __half22float2(raw.z);
            const float2 f3 = __half22float2(raw.w);
            acc[0] += f0.x; acc[1] += f0.y;
            acc[2] += f1.x; acc[3] += f1.y;
            acc[4] += f2.x; acc[5] += f2.y;
            acc[6] += f3.x; acc[7] += f3.y;
        }
#pragma unroll
        for (int d = 0; d < 8; ++d) acc[d] += __shfl_xor(acc[d], 4, 64);
#pragma unroll
        for (int d = 0; d < 8; ++d) acc[d] += __shfl_xor(acc[d], 8, 64);
        *(float2*)&X[m][32 + 8 * k + 2 * h] =
            make_float2(acc[2 * h] * (1.0f / 16.0f),
                        acc[2 * h + 1] * (1.0f / 16.0f));
    }

    // ---- phase C: convert + store hop1/user rows (b128 writes) ----
    if (cact) {
        const float2 fa = __half22float2(craw.x);
        const float2 fb = __half22float2(craw.y);
        *(float4*)&X[g][4 * k8] = make_float4(fa.x, fa.y, fb.x, fb.y);
    }
    __syncthreads();   // barrier 1: X, Ws, bs all visible

    // ---- mean1 -> X[16][32..63] (read later only by wave 0) ----
    if (t < 32) {
        float mn = 0.0f;
#pragma unroll
        for (int m2 = 0; m2 < 16; ++m2) mn += X[m2][t];
        X[16][32 + t] = mn * (1.0f / 16.0f);
    }

    // ---- phase D: 2 nodes per thread, vsum in registers ----
    {
        const int o = t & 31;
        const int h = (t >> 5) & 1;
        const int w = t >> 6;
        const int n0 = 4 * w + 2 * h, n1 = n0 + 1;
        float a0 = bs[o], a1 = a0;
#pragma unroll 4
        for (int dc = 0; dc < 16; ++dc) {
            const float4 wv = *(const float4*)&Ws[o][4 * WCH(o, dc)];
            const float4 x0 = *(const float4*)&X[n0][4 * dc];
            const float4 x1 = *(const float4*)&X[n1][4 * dc];
            a0 += wv.x * x0.x + wv.y * x0.y + wv.z * x0.z + wv.w * x0.w;
            a1 += wv.x * x1.x + wv.y * x1.y + wv.z * x1.z + wv.w * x1.w;
        }
        float vsum = fmaxf(a0, 0.0f) + fmaxf(a1, 0.0f);
        vsum += __shfl_xor(vsum, 32, 64);
        if (h == 0) vpart[w][o] = vsum;
    }
    __syncthreads();   // barrier 2: vpart visible to wave 0

    // ---- final phase: wave 0 only (same-wave LDS ordering, no barrier) ----
    if (t < 64) {
        const int o = t & 31, pr = t >> 5;
        if (pr == 0) {
            // v0 = relu(W [u | mean1] + b)
            float a = bs[o];
#pragma unroll 4
            for (int dc = 0; dc < 16; ++dc) {
                const float4 wv = *(const float4*)&Ws[o][4 * WCH(o, dc)];
                const float4 xv = *(const float4*)&X[16][4 * dc];
                a += wv.x * xv.x + wv.y * xv.y + wv.z * xv.z + wv.w * xv.w;
            }
            xe[o] = fmaxf(a, 0.0f);
        } else {
            xe[32 + o] = (vpart[0][o] + vpart[1][o] + vpart[2][o] +
                          vpart[3][o]) * (1.0f / 16.0f);
        }
        // E: each half covers 8 chunks, combine across halves
        float a = 0.0f;
#pragma unroll 4
        for (int dc = 8 * pr; dc < 8 * pr + 8; ++dc) {
            const float4 wv = *(const float4*)&Ws[o][4 * WCH(o, dc)];
            const float4 xv = *(const float4*)&xe[4 * dc];
            a += wv.x * xv.x + wv.y * xv.y + wv.z * xv.z + wv.w * xv.w;
        }
        a += __shfl_xor(a, 32, 64);
        if (pr == 0)
            res[(b * RULESC + r) * DIMC + o] = tanhf(a + bs[o]);
    }
}

// ---------------------------------------------------------------------------
// Kernel 2: one wave per batch element — rule-weighted sum + item dot+sigmoid
// ---------------------------------------------------------------------------
__global__ __launch_bounds__(256) void rgrec_combine_kernel(
    const int* __restrict__ items, const float* __restrict__ emb,
    const float* __restrict__ rule_w, const float* __restrict__ res,
    float* __restrict__ out, int B)
{
    const int gw = (blockIdx.x * 256 + threadIdx.x) >> 6;
    const int lane = threadIdx.x & 63;
    if (gw >= B) return;
    const int b = gw;

    float ss = 0.0f;
#pragma unroll
    for (int i = 0; i < RULESC; ++i) { const float w = rule_w[i]; ss += w * w; }
    const float rws = fminf(1.0f, 1.0f / fmaxf(sqrtf(ss), 1e-7f));

    const int d = lane & 31, rh = lane >> 5;
    float acc = 0.0f;
#pragma unroll
    for (int rr = 0; rr < 4; ++rr) {
        const int r = rh * 4 + rr;
        acc += rule_w[r] * res[(b * RULESC + r) * DIMC + d];
    }
    acc += __shfl_xor(acc, 32, 64);
    acc *= rws;

    const int it = items[b];
    const float x = emb[(long)it * DIMC + d];
    float sq = x * x;
    sq += __shfl_xor(sq, 1, 64);
    sq += __shfl_xor(sq, 2, 64);
    sq += __shfl_xor(sq, 4, 64);
    sq += __shfl_xor(sq, 8, 64);
    sq += __shfl_xor(sq, 16, 64);
    const float s = fminf(1.0f, 1.0f / fmaxf(sqrtf(sq), 1e-7f));
    float p = acc * x * s;
    p += __shfl_xor(p, 1, 64);
    p += __shfl_xor(p, 2, 64);
    p += __shfl_xor(p, 4, 64);
    p += __shfl_xor(p, 8, 64);
    p += __shfl_xor(p, 16, 64);
    if (lane == 0) out[b] = 1.0f / (1.0f + expf(-p));
}

// ---------------------------------------------------------------------------
// Fallback fused fp32 kernel (known-good) if d_ws is too small.
// ---------------------------------------------------------------------------
__global__ __launch_bounds__(256) void rgrec_fused_kernel(
    const int* __restrict__ users, const int* __restrict__ items,
    const int* __restrict__ rules, const int* __restrict__ adj,
    const float* __restrict__ emb, const float* __restrict__ rule_w,
    const float* __restrict__ W, const float* __restrict__ bvec,
    float* __restrict__ out)
{
    const int b = blockIdx.x;
    const int t = threadIdx.x;

    __shared__ float Wt[64][33];
    __shared__ float bs[32];
    __shared__ float h1s[16][33];
    __shared__ float mean2[16][33];
    __shared__ float v1[16][33];
    __shared__ float u_vec[32];
    __shared__ float mean1[32];
    __shared__ float v0[32];
    __shared__ float meanv1[32];
    __shared__ float useru[32];
    __shared__ int   h1id[16];

    for (int i = t; i < 64 * 32; i += 256) {
        const int o = i >> 6, d = i & 63;
        Wt[d][o] = W[i];
    }
    if (t < 32) { bs[t] = bvec[t]; useru[t] = 0.0f; }

    float ss = 0.0f;
#pragma unroll
    for (int i = 0; i < RULESC; ++i) { const float w = rule_w[i]; ss += w * w; }
    const float rws = fminf(1.0f, 1.0f / fmaxf(sqrtf(ss), 1e-7f));

    const int user = users[b];

    for (int r = 0; r < RULESC; ++r) {
        const int rid0 = rules[r * 2 + 0];
        const int rid1 = rules[r * 2 + 1];
        if (t < 16) h1id[t] = adj[(rid0 * E_NUMC + user) * NEIGHC + t];
        __syncthreads();
        {
            const int m = t >> 4, j = t & 15;
            const int e1 = h1id[m];
            const int e2 = adj[(rid1 * E_NUMC + e1) * NEIGHC + j];
            float v[32];
            const float4* p = (const float4*)(emb + (long)e2 * DIMC);
            float sq = 0.0f;
#pragma unroll
            for (int q = 0; q < 8; ++q) {
                const float4 f = p[q];
                v[q * 4 + 0] = f.x; v[q * 4 + 1] = f.y;
                v[q * 4 + 2] = f.z; v[q * 4 + 3] = f.w;
                sq += f.x * f.x + f.y * f.y + f.z * f.z + f.w * f.w;
            }
            const float s =
                fminf(1.0f, 1.0f / fmaxf(sqrtf(sq), 1e-7f)) * (1.0f / 16.0f);
#pragma unroll
            for (int d = 0; d < 32; ++d) v[d] *= s;
#pragma unroll
            for (int st = 1; st < 16; st <<= 1) {
#pragma unroll
                for (int d = 0; d < 32; ++d) v[d] += __shfl_xor(v[d], st, 64);
            }
            mean2[m][j]      = v[j];
            mean2[m][j + 16] = v[j + 16];
        }
        if (t < 136) {
            const int g = t >> 3, k = t & 7;
            const int e = (g < 16) ? h1id[g] : user;
            const float4 f = ((const float4*)(emb + (long)e * DIMC))[k];
            float sq = f.x * f.x + f.y * f.y + f.z * f.z + f.w * f.w;
            sq += __shfl_xor(sq, 1, 64);
            sq += __shfl_xor(sq, 2, 64);
            sq += __shfl_xor(sq, 4, 64);
            const float s = fminf(1.0f, 1.0f / fmaxf(sqrtf(sq), 1e-7f));
            if (g < 16) {
                h1s[g][k * 4 + 0] = f.x * s; h1s[g][k * 4 + 1] = f.y * s;
                h1s[g][k * 4 + 2] = f.z * s; h1s[g][k * 4 + 3] = f.w * s;
            } else {
                u_vec[k * 4 + 0] = f.x * s; u_vec[k * 4 + 1] = f.y * s;
                u_vec[k * 4 + 2] = f.z * s; u_vec[k * 4 + 3] = f.w * s;
            }
        }
        __syncthreads();
        {
            const int m = t >> 4, o = t & 15;
            float a0 = bs[o], a1 = bs[o + 16];
#pragma unroll
            for (int d = 0; d < 32; ++d) {
                const float h = h1s[m][d];
                a0 += Wt[d][o] * h;
                a1 += Wt[d][o + 16] * h;
            }
#pragma unroll
            for (int d = 0; d < 32; ++d) {
                const float h = mean2[m][d];
                a0 += Wt[32 + d][o] * h;
                a1 += Wt[32 + d][o + 16] * h;
            }
            v1[m][o]      = fmaxf(a0, 0.0f);
            v1[m][o + 16] = fmaxf(a1, 0.0f);
        }
        if (t < 32) {
            float mn = 0.0f;
#pragma unroll
            for (int m2 = 0; m2 < 16; ++m2) mn += h1s[m2][t];
            mean1[t] = mn * (1.0f / 16.0f);
        }
        __syncthreads();
        if (t < 32) {
            float a = bs[t];
#pragma unroll
            for (int d = 0; d < 32; ++d) a += Wt[d][t] * u_vec[d];
#pragma unroll
            for (int d = 0; d < 32; ++d) a += Wt[32 + d][t] * mean1[d];
            v0[t] = fmaxf(a, 0.0f);
            float mv = 0.0f;
#pragma unroll
            for (int m2 = 0; m2 < 16; ++m2) mv += v1[m2][t];
            meanv1[t] = mv * (1.0f / 16.0f);
        }
        __syncthreads();
        if (t < 32) {
            float a = bs[t];
#pragma unroll
            for (int d = 0; d < 32; ++d) a += Wt[d][t] * v0[d];
#pragma unroll
            for (int d = 0; d < 32; ++d) a += Wt[32 + d][t] * meanv1[d];
            useru[t] += rule_w[r] * rws * tanhf(a);
        }
        __syncthreads();
    }

    if (t < 32) {
        const int it = items[b];
        const float x = emb[(long)it * DIMC + t];
        float sq = x * x;
        sq += __shfl_xor(sq, 1, 64);
        sq += __shfl_xor(sq, 2, 64);
        sq += __shfl_xor(sq, 4, 64);
        sq += __shfl_xor(sq, 8, 64);
        sq += __shfl_xor(sq, 16, 64);
        const float s = fminf(1.0f, 1.0f / fmaxf(sqrtf(sq), 1e-7f));
        float p = useru[t] * x * s;
        p += __shfl_xor(p, 1, 64);
        p += __shfl_xor(p, 2, 64);
        p += __shfl_xor(p, 4, 64);
        p += __shfl_xor(p, 8, 64);
        p += __shfl_xor(p, 16, 64);
        if (t == 0) out[b] = 1.0f / (1.0f + expf(-p));
    }
}

extern "C" void kernel_launch(void* const* d_in, const int* in_sizes, int n_in,
                              void* d_out, int out_size, void* d_ws, size_t ws_size,
                              hipStream_t stream) {
    const int*   users  = (const int*)d_in[0];
    const int*   items  = (const int*)d_in[1];
    const int*   rules  = (const int*)d_in[2];
    const int*   adj    = (const int*)d_in[3];
    const float* emb    = (const float*)d_in[4];
    const float* rule_w = (const float*)d_in[5];
    const float* W      = (const float*)d_in[6];
    const float* bvec   = (const float*)d_in[7];
    float*       out    = (float*)d_out;

    const int batch = in_sizes[0];  // 1024
    const size_t emb16_bytes = (size_t)E_NUMC * DIMC * sizeof(__half);  // 6.4 MB
    const size_t res_bytes   = (size_t)batch * RULESC * DIMC * sizeof(float);

    if (ws_size >= emb16_bytes + res_bytes) {
        __half2* emb16 = (__half2*)d_ws;
        float*   res   = (float*)((char*)d_ws + emb16_bytes);

        renorm_f16_kernel<<<dim3(E_NUMC / 16), dim3(256), 0, stream>>>(
            emb, emb16);
        rgrec_tree16_kernel<<<dim3(batch, RULESC), dim3(256), 0, stream>>>(
            users, rules, adj, emb16, W, bvec, res);
        const int nblk = (batch * 64 + 255) / 256;
        rgrec_combine_kernel<<<dim3(nblk), dim3(256), 0, stream>>>(
            items, emb, rule_w, res, out, batch);
    } else {
        rgrec_fused_kernel<<<dim3(batch), dim3(256), 0, stream>>>(
            users, items, rules, adj, emb, rule_w, W, bvec, out);
    }
}

// Round 7
// 41.650 us; speedup vs baseline: 2.2844x; 1.3265x over previous
//
#include <hip/hip_runtime.h>
#include <hip/hip_fp16.h>
#include <math.h>

#define E_NUMC 100000
#define DIMC 32
#define NEIGHC 16
#define RULESC 8

struct __align__(16) h2x4 { __half2 x, y, z, w; };
struct __align__(8)  h2x2 { __half2 x, y; };

typedef _Float16 half8 __attribute__((ext_vector_type(8)));
typedef float    floatx4 __attribute__((ext_vector_type(4)));

// ---------------------------------------------------------------------------
// Pre-pass: renormed fp16 embedding table in d_ws. 16 lanes per row.
// ---------------------------------------------------------------------------
__global__ __launch_bounds__(256) void renorm_f16_kernel(
    const float* __restrict__ emb, __half2* __restrict__ o16)
{
    const int row = blockIdx.x * 16 + (threadIdx.x >> 4);
    const int j = threadIdx.x & 15;
    const float2 f = ((const float2*)(emb + (long)row * DIMC))[j];
    float sq = f.x * f.x + f.y * f.y;
    sq += __shfl_xor(sq, 1, 64);
    sq += __shfl_xor(sq, 2, 64);
    sq += __shfl_xor(sq, 4, 64);
    sq += __shfl_xor(sq, 8, 64);
    const float s = fminf(1.0f, 1.0f / fmaxf(sqrtf(sq), 1e-7f));
    o16[(long)row * (DIMC / 2) + j] = __floats2half2_rn(f.x * s, f.y * s);
}

// ---------------------------------------------------------------------------
// Kernel 1: one (batch, rule) tree per 256-thread block. 2 barriers.
// Phase D is a 16x32x64 GEMM done with 4 x mfma_f32_16x16x32_f16:
//   A = Xh (16 node rows x 64 dims fp16), B = W^T (B[k][n] = W[n][k], read as
//   Wh[n][k-octet] b128), C-frag: col=lane&15 (out), row=4*(lane>>4)+reg (node).
// v1 never hits LDS: relu+bias+column-sum in the C fragment -> meanv1.
// Wave 2 computes the user/v0 row via VALU; wave 3 idles in the MLP.
// ---------------------------------------------------------------------------
__global__ __launch_bounds__(256, 6) void rgrec_tree16_kernel(
    const int* __restrict__ users, const int* __restrict__ rules,
    const int* __restrict__ adj, const __half2* __restrict__ emb16,
    const float* __restrict__ W, const float* __restrict__ bvec,
    float* __restrict__ res)
{
    const int b = blockIdx.x;
    const int r = blockIdx.y;
    const int t = threadIdx.x;
    const int lane = t & 63;
    const int wave = t >> 6;

    __shared__ _Float16 Xh[16][72];     // node rows: [h1 | mean2], 144B pitch
    __shared__ _Float16 Wh[32][72];     // W rows fp16, 144B pitch
    __shared__ _Float16 u16[72];        // user row (renormed)
    __shared__ float mean1p[2][36];     // partial sums of h1 rows (x8 each)
    __shared__ float xe[68];            // [v0 | meanv1]
    __shared__ float bs[32];

    const int user = users[b];
    const int rid0 = rules[r * 2 + 0];
    const int rid1 = rules[r * 2 + 1];

    // longest dependency chain first: hop1 ids (per-wave, no barrier)
    int h1v = 0;
    if (lane < 16) h1v = adj[(rid0 * E_NUMC + user) * NEIGHC + lane];

    // ---- phase B ids: node m, child j ----
    const int m = t >> 4;
    const int j = t & 15;
    const int e1 = __shfl(h1v, m, 64);
    const int e2 = adj[(rid1 * E_NUMC + e1) * NEIGHC + j];

    // ---- phase C loads issued early: 17 rows, 8 B/lane ----
    const int g = t >> 3, k8 = t & 7;
    const bool cact = (t < 136);
    h2x2 craw;
    if (cact) {
        const int ec = (g < 16) ? __shfl(h1v, g, 64) : user;
        craw = ((const h2x2*)(emb16 + (long)ec * (DIMC / 2)))[k8];
    }

    // ---- stage W as fp16: thread -> (o = t>>3, oct = t&7), 8 floats ----
    {
        const float4* W4 = (const float4*)W;
        const int o = t >> 3, oct = t & 7;
        const float4 wa = W4[o * 16 + 2 * oct];
        const float4 wb = W4[o * 16 + 2 * oct + 1];
        half8 hw;
        hw[0] = (_Float16)wa.x; hw[1] = (_Float16)wa.y;
        hw[2] = (_Float16)wa.z; hw[3] = (_Float16)wa.w;
        hw[4] = (_Float16)wb.x; hw[5] = (_Float16)wb.y;
        hw[6] = (_Float16)wb.z; hw[7] = (_Float16)wb.w;
        *(half8*)&Wh[o][8 * oct] = hw;
    }
    if (t < 32) bs[t] = bvec[t];

    // ---- phase B: dwordx4 gather + fp32 accumulate + 2-step butterfly ----
    {
        const int k = j & 3;        // 16-B chunk: dims 8k..8k+7
        const int h = j >> 2;       // child subset
        const int gbase = t & 48;   // wave-local base lane of this node group
        float acc[8];
#pragma unroll
        for (int d = 0; d < 8; ++d) acc[d] = 0.0f;
#pragma unroll
        for (int i = 0; i < 4; ++i) {
            const int ec = __shfl(e2, gbase + h + 4 * i, 64);
            const h2x4 raw = ((const h2x4*)(emb16 + (long)ec * (DIMC / 2)))[k];
            const float2 f0 = __half22float2(raw.x);
            const float2 f1 = __half22float2(raw.y);
            const float2 f2 = __half22float2(raw.z);
            const float2 f3 = __half22float2(raw.w);
            acc[0] += f0.x; acc[1] += f0.y;
            acc[2] += f1.x; acc[3] += f1.y;
            acc[4] += f2.x; acc[5] += f2.y;
            acc[6] += f3.x; acc[7] += f3.y;
        }
#pragma unroll
        for (int d = 0; d < 8; ++d) acc[d] += __shfl_xor(acc[d], 4, 64);
#pragma unroll
        for (int d = 0; d < 8; ++d) acc[d] += __shfl_xor(acc[d], 8, 64);
        *(__half2*)&Xh[m][32 + 8 * k + 2 * h] =
            __floats2half2_rn(acc[2 * h] * (1.0f / 16.0f),
                              acc[2 * h + 1] * (1.0f / 16.0f));
    }

    // ---- phase C: store hop1/user rows + mean1 partial reduction ----
    if (cact) {
        if (g < 16) *(h2x2*)&Xh[g][4 * k8] = craw;
        else        *(h2x2*)&u16[4 * k8] = craw;
    }
    if (t < 128) {
        const float2 fa = __half22float2(craw.x);
        const float2 fb = __half22float2(craw.y);
        float c0 = fa.x, c1 = fa.y, c2 = fb.x, c3 = fb.y;
#pragma unroll
        for (int st = 8; st <= 32; st <<= 1) {
            c0 += __shfl_xor(c0, st, 64);
            c1 += __shfl_xor(c1, st, 64);
            c2 += __shfl_xor(c2, st, 64);
            c3 += __shfl_xor(c3, st, 64);
        }
        if ((lane & 56) == 0)   // lane < 8 (= k8)
            *(float4*)&mean1p[wave][4 * k8] = make_float4(c0, c1, c2, c3);
    }
    __syncthreads();   // barrier 1: Xh, u16, Wh, bs, mean1p visible

    const int cn = lane & 15;      // col (out) / row-id within fragments
    const int kg = lane >> 4;      // k-octet group
    if (wave < 2) {
        // ---- phase D: 16 nodes x 16 outs (N-half = wave), K = 64 ----
        const half8 a0 = *(const half8*)&Xh[cn][8 * kg];
        const half8 a1 = *(const half8*)&Xh[cn][32 + 8 * kg];
        const half8 b0 = *(const half8*)&Wh[cn + 16 * wave][8 * kg];
        const half8 b1 = *(const half8*)&Wh[cn + 16 * wave][32 + 8 * kg];
        floatx4 acc = {0.0f, 0.0f, 0.0f, 0.0f};
        acc = __builtin_amdgcn_mfma_f32_16x16x32_f16(a0, b0, acc, 0, 0, 0);
        acc = __builtin_amdgcn_mfma_f32_16x16x32_f16(a1, b1, acc, 0, 0, 0);
        const float bb = bs[cn + 16 * wave];
        float csum = 0.0f;
#pragma unroll
        for (int q = 0; q < 4; ++q) csum += fmaxf(acc[q] + bb, 0.0f);
        csum += __shfl_xor(csum, 16, 64);
        csum += __shfl_xor(csum, 32, 64);
        if (lane < 16) xe[32 + cn + 16 * wave] = csum * (1.0f / 16.0f);
    } else if (wave == 2) {
        // ---- v0 = relu(W [u | mean1] + b), split across d-halves ----
        const int o = lane & 31, h = lane >> 5;
        float a = 0.0f;
        if (h == 0) {
#pragma unroll
            for (int oct = 0; oct < 4; ++oct) {
                const half8 u = *(const half8*)&u16[8 * oct];
                const half8 w = *(const half8*)&Wh[o][8 * oct];
#pragma unroll
                for (int q = 0; q < 8; ++q) a += (float)u[q] * (float)w[q];
            }
        } else {
#pragma unroll
            for (int oct = 0; oct < 4; ++oct) {
                const half8 w = *(const half8*)&Wh[o][32 + 8 * oct];
                const float4 p0a = *(const float4*)&mean1p[0][8 * oct];
                const float4 p0b = *(const float4*)&mean1p[0][8 * oct + 4];
                const float4 p1a = *(const float4*)&mean1p[1][8 * oct];
                const float4 p1b = *(const float4*)&mean1p[1][8 * oct + 4];
                a += (float)w[0] * (p0a.x + p1a.x) + (float)w[1] * (p0a.y + p1a.y)
                   + (float)w[2] * (p0a.z + p1a.z) + (float)w[3] * (p0a.w + p1a.w)
                   + (float)w[4] * (p0b.x + p1b.x) + (float)w[5] * (p0b.y + p1b.y)
                   + (float)w[6] * (p0b.z + p1b.z) + (float)w[7] * (p0b.w + p1b.w);
            }
            a *= (1.0f / 16.0f);   // mean1 partials are sums over 16 rows
        }
        a += __shfl_xor(a, 32, 64);
        if (h == 0) xe[o] = fmaxf(a + bs[o], 0.0f);
    }
    __syncthreads();   // barrier 2: xe ready

    // ---- phase E: wave 0, out o, halves over d ----
    if (t < 64) {
        const int o = lane & 31, h = lane >> 5;
        float a = 0.0f;
#pragma unroll
        for (int oct = 4 * h; oct < 4 * h + 4; ++oct) {
            const half8 w = *(const half8*)&Wh[o][8 * oct];
            const float4 xa = *(const float4*)&xe[8 * oct];
            const float4 xb = *(const float4*)&xe[8 * oct + 4];
            a += (float)w[0] * xa.x + (float)w[1] * xa.y
               + (float)w[2] * xa.z + (float)w[3] * xa.w
               + (float)w[4] * xb.x + (float)w[5] * xb.y
               + (float)w[6] * xb.z + (float)w[7] * xb.w;
        }
        a += __shfl_xor(a, 32, 64);
        if (h == 0)
            res[(b * RULESC + r) * DIMC + o] = tanhf(a + bs[o]);
    }
}

// ---------------------------------------------------------------------------
// Kernel 2: one wave per batch element — rule-weighted sum + item dot+sigmoid
// ---------------------------------------------------------------------------
__global__ __launch_bounds__(256) void rgrec_combine_kernel(
    const int* __restrict__ items, const float* __restrict__ emb,
    const float* __restrict__ rule_w, const float* __restrict__ res,
    float* __restrict__ out, int B)
{
    const int gw = (blockIdx.x * 256 + threadIdx.x) >> 6;
    const int lane = threadIdx.x & 63;
    if (gw >= B) return;
    const int b = gw;

    float ss = 0.0f;
#pragma unroll
    for (int i = 0; i < RULESC; ++i) { const float w = rule_w[i]; ss += w * w; }
    const float rws = fminf(1.0f, 1.0f / fmaxf(sqrtf(ss), 1e-7f));

    const int d = lane & 31, rh = lane >> 5;
    float acc = 0.0f;
#pragma unroll
    for (int rr = 0; rr < 4; ++rr) {
        const int r = rh * 4 + rr;
        acc += rule_w[r] * res[(b * RULESC + r) * DIMC + d];
    }
    acc += __shfl_xor(acc, 32, 64);
    acc *= rws;

    const int it = items[b];
    const float x = emb[(long)it * DIMC + d];
    float sq = x * x;
    sq += __shfl_xor(sq, 1, 64);
    sq += __shfl_xor(sq, 2, 64);
    sq += __shfl_xor(sq, 4, 64);
    sq += __shfl_xor(sq, 8, 64);
    sq += __shfl_xor(sq, 16, 64);
    const float s = fminf(1.0f, 1.0f / fmaxf(sqrtf(sq), 1e-7f));
    float p = acc * x * s;
    p += __shfl_xor(p, 1, 64);
    p += __shfl_xor(p, 2, 64);
    p += __shfl_xor(p, 4, 64);
    p += __shfl_xor(p, 8, 64);
    p += __shfl_xor(p, 16, 64);
    if (lane == 0) out[b] = 1.0f / (1.0f + expf(-p));
}

// ---------------------------------------------------------------------------
// Fallback fused fp32 kernel (known-good) if d_ws is too small.
// ---------------------------------------------------------------------------
__global__ __launch_bounds__(256) void rgrec_fused_kernel(
    const int* __restrict__ users, const int* __restrict__ items,
    const int* __restrict__ rules, const int* __restrict__ adj,
    const float* __restrict__ emb, const float* __restrict__ rule_w,
    const float* __restrict__ W, const float* __restrict__ bvec,
    float* __restrict__ out)
{
    const int b = blockIdx.x;
    const int t = threadIdx.x;

    __shared__ float Wt[64][33];
    __shared__ float bs[32];
    __shared__ float h1s[16][33];
    __shared__ float mean2[16][33];
    __shared__ float v1[16][33];
    __shared__ float u_vec[32];
    __shared__ float mean1[32];
    __shared__ float v0[32];
    __shared__ float meanv1[32];
    __shared__ float useru[32];
    __shared__ int   h1id[16];

    for (int i = t; i < 64 * 32; i += 256) {
        const int o = i >> 6, d = i & 63;
        Wt[d][o] = W[i];
    }
    if (t < 32) { bs[t] = bvec[t]; useru[t] = 0.0f; }

    float ss = 0.0f;
#pragma unroll
    for (int i = 0; i < RULESC; ++i) { const float w = rule_w[i]; ss += w * w; }
    const float rws = fminf(1.0f, 1.0f / fmaxf(sqrtf(ss), 1e-7f));

    const int user = users[b];

    for (int r = 0; r < RULESC; ++r) {
        const int rid0 = rules[r * 2 + 0];
        const int rid1 = rules[r * 2 + 1];
        if (t < 16) h1id[t] = adj[(rid0 * E_NUMC + user) * NEIGHC + t];
        __syncthreads();
        {
            const int m = t >> 4, j = t & 15;
            const int e1 = h1id[m];
            const int e2 = adj[(rid1 * E_NUMC + e1) * NEIGHC + j];
            float v[32];
            const float4* p = (const float4*)(emb + (long)e2 * DIMC);
            float sq = 0.0f;
#pragma unroll
            for (int q = 0; q < 8; ++q) {
                const float4 f = p[q];
                v[q * 4 + 0] = f.x; v[q * 4 + 1] = f.y;
                v[q * 4 + 2] = f.z; v[q * 4 + 3] = f.w;
                sq += f.x * f.x + f.y * f.y + f.z * f.z + f.w * f.w;
            }
            const float s =
                fminf(1.0f, 1.0f / fmaxf(sqrtf(sq), 1e-7f)) * (1.0f / 16.0f);
#pragma unroll
            for (int d = 0; d < 32; ++d) v[d] *= s;
#pragma unroll
            for (int st = 1; st < 16; st <<= 1) {
#pragma unroll
                for (int d = 0; d < 32; ++d) v[d] += __shfl_xor(v[d], st, 64);
            }
            mean2[m][j]      = v[j];
            mean2[m][j + 16] = v[j + 16];
        }
        if (t < 136) {
            const int g = t >> 3, k = t & 7;
            const int e = (g < 16) ? h1id[g] : user;
            const float4 f = ((const float4*)(emb + (long)e * DIMC))[k];
            float sq = f.x * f.x + f.y * f.y + f.z * f.z + f.w * f.w;
            sq += __shfl_xor(sq, 1, 64);
            sq += __shfl_xor(sq, 2, 64);
            sq += __shfl_xor(sq, 4, 64);
            const float s = fminf(1.0f, 1.0f / fmaxf(sqrtf(sq), 1e-7f));
            if (g < 16) {
                h1s[g][k * 4 + 0] = f.x * s; h1s[g][k * 4 + 1] = f.y * s;
                h1s[g][k * 4 + 2] = f.z * s; h1s[g][k * 4 + 3] = f.w * s;
            } else {
                u_vec[k * 4 + 0] = f.x * s; u_vec[k * 4 + 1] = f.y * s;
                u_vec[k * 4 + 2] = f.z * s; u_vec[k * 4 + 3] = f.w * s;
            }
        }
        __syncthreads();
        {
            const int m = t >> 4, o = t & 15;
            float a0 = bs[o], a1 = bs[o + 16];
#pragma unroll
            for (int d = 0; d < 32; ++d) {
                const float h = h1s[m][d];
                a0 += Wt[d][o] * h;
                a1 += Wt[d][o + 16] * h;
            }
#pragma unroll
            for (int d = 0; d < 32; ++d) {
                const float h = mean2[m][d];
                a0 += Wt[32 + d][o] * h;
                a1 += Wt[32 + d][o + 16] * h;
            }
            v1[m][o]      = fmaxf(a0, 0.0f);
            v1[m][o + 16] = fmaxf(a1, 0.0f);
        }
        if (t < 32) {
            float mn = 0.0f;
#pragma unroll
            for (int m2 = 0; m2 < 16; ++m2) mn += h1s[m2][t];
            mean1[t] = mn * (1.0f / 16.0f);
        }
        __syncthreads();
        if (t < 32) {
            float a = bs[t];
#pragma unroll
            for (int d = 0; d < 32; ++d) a += Wt[d][t] * u_vec[d];
#pragma unroll
            for (int d = 0; d < 32; ++d) a += Wt[32 + d][t] * mean1[d];
            v0[t] = fmaxf(a, 0.0f);
            float mv = 0.0f;
#pragma unroll
            for (int m2 = 0; m2 < 16; ++m2) mv += v1[m2][t];
            meanv1[t] = mv * (1.0f / 16.0f);
        }
        __syncthreads();
        if (t < 32) {
            float a = bs[t];
#pragma unroll
            for (int d = 0; d < 32; ++d) a += Wt[d][t] * v0[d];
#pragma unroll
            for (int d = 0; d < 32; ++d) a += Wt[32 + d][t] * meanv1[d];
            useru[t] += rule_w[r] * rws * tanhf(a);
        }
        __syncthreads();
    }

    if (t < 32) {
        const int it = items[b];
        const float x = emb[(long)it * DIMC + t];
        float sq = x * x;
        sq += __shfl_xor(sq, 1, 64);
        sq += __shfl_xor(sq, 2, 64);
        sq += __shfl_xor(sq, 4, 64);
        sq += __shfl_xor(sq, 8, 64);
        sq += __shfl_xor(sq, 16, 64);
        const float s = fminf(1.0f, 1.0f / fmaxf(sqrtf(sq), 1e-7f));
        float p = useru[t] * x * s;
        p += __shfl_xor(p, 1, 64);
        p += __shfl_xor(p, 2, 64);
        p += __shfl_xor(p, 4, 64);
        p += __shfl_xor(p, 8, 64);
        p += __shfl_xor(p, 16, 64);
        if (t == 0) out[b] = 1.0f / (1.0f + expf(-p));
    }
}

extern "C" void kernel_launch(void* const* d_in, const int* in_sizes, int n_in,
                              void* d_out, int out_size, void* d_ws, size_t ws_size,
                              hipStream_t stream) {
    const int*   users  = (const int*)d_in[0];
    const int*   items  = (const int*)d_in[1];
    const int*   rules  = (const int*)d_in[2];
    const int*   adj    = (const int*)d_in[3];
    const float* emb    = (const float*)d_in[4];
    const float* rule_w = (const float*)d_in[5];
    const float* W      = (const float*)d_in[6];
    const float* bvec   = (const float*)d_in[7];
    float*       out    = (float*)d_out;

    const int batch = in_sizes[0];  // 1024
    const size_t emb16_bytes = (size_t)E_NUMC * DIMC * sizeof(__half);  // 6.4 MB
    const size_t res_bytes   = (size_t)batch * RULESC * DIMC * sizeof(float);

    if (ws_size >= emb16_bytes + res_bytes) {
        __half2* emb16 = (__half2*)d_ws;
        float*   res   = (float*)((char*)d_ws + emb16_bytes);

        renorm_f16_kernel<<<dim3(E_NUMC / 16), dim3(256), 0, stream>>>(
            emb, emb16);
        rgrec_tree16_kernel<<<dim3(batch, RULESC), dim3(256), 0, stream>>>(
            users, rules, adj, emb16, W, bvec, res);
        const int nblk = (batch * 64 + 255) / 256;
        rgrec_combine_kernel<<<dim3(nblk), dim3(256), 0, stream>>>(
            items, emb, rule_w, res, out, batch);
    } else {
        rgrec_fused_kernel<<<dim3(batch), dim3(256), 0, stream>>>(
            users, items, rules, adj, emb, rule_w, W, bvec, out);
    }
}

// Round 8
// 37.592 us; speedup vs baseline: 2.5310x; 1.1079x over previous
//
#include <hip/hip_runtime.h>
#include <hip/hip_fp16.h>
#include <math.h>

#define E_NUMC 100000
#define DIMC 32
#define NEIGHC 16
#define RULESC 8

struct __align__(16) h2x4 { __half2 x, y, z, w; };
struct __align__(8)  h2x2 { __half2 x, y; };

typedef _Float16 half8 __attribute__((ext_vector_type(8)));
typedef float    floatx4 __attribute__((ext_vector_type(4)));
typedef float    fx2 __attribute__((ext_vector_type(2)));

// ---------------------------------------------------------------------------
// Pre-pass: renormed embedding tables in d_ws.
//   emb16: fp16, 64 B/row  (hop1/user reads - accuracy-sensitive, unaveraged)
//   emb8:  fp8 e4m3, 32 B/row (hop2 reads - averaged over 16, 3.2 MB table
//          fits the 4 MB per-XCD L2 -> gathers become L2 hits)
// 16 lanes per row; lane j owns dims (2j, 2j+1).
// ---------------------------------------------------------------------------
__global__ __launch_bounds__(256) void renorm_kernel(
    const float* __restrict__ emb, __half2* __restrict__ o16,
    short* __restrict__ o8)
{
    const int row = blockIdx.x * 16 + (threadIdx.x >> 4);
    const int j = threadIdx.x & 15;
    const float2 f = ((const float2*)(emb + (long)row * DIMC))[j];
    float sq = f.x * f.x + f.y * f.y;
    sq += __shfl_xor(sq, 1, 64);
    sq += __shfl_xor(sq, 2, 64);
    sq += __shfl_xor(sq, 4, 64);
    sq += __shfl_xor(sq, 8, 64);
    const float s = fminf(1.0f, 1.0f / fmaxf(sqrtf(sq), 1e-7f));
    const float vx = f.x * s, vy = f.y * s;
    o16[(long)row * (DIMC / 2) + j] = __floats2half2_rn(vx, vy);
    const int pk = __builtin_amdgcn_cvt_pk_fp8_f32(vx, vy, 0, false);
    o8[(long)row * (DIMC / 2) + j] = (short)(pk & 0xffff);
}

// ---------------------------------------------------------------------------
// Kernel 1: one (batch, rule) tree per 256-thread block. 2 barriers.
// Phase B gathers hop2 rows from the fp8 table (uint2 = 8 dims per load),
// decodes with v_cvt_pk_f32_fp8, fp32-accumulates, 2-step butterfly.
// Phase D is a 16x32x64 GEMM via 4 x mfma_f32_16x16x32_f16 (C-frag:
// col=lane&15, row=4*(lane>>4)+reg); relu+bias+column-sum in-fragment
// produces meanv1 without materializing v1.
// ---------------------------------------------------------------------------
__global__ __launch_bounds__(256, 6) void rgrec_tree16_kernel(
    const int* __restrict__ users, const int* __restrict__ rules,
    const int* __restrict__ adj, const __half2* __restrict__ emb16,
    const uint2* __restrict__ emb8, const float* __restrict__ W,
    const float* __restrict__ bvec, float* __restrict__ res)
{
    const int b = blockIdx.x;
    const int r = blockIdx.y;
    const int t = threadIdx.x;
    const int lane = t & 63;
    const int wave = t >> 6;

    __shared__ _Float16 Xh[16][72];     // node rows: [h1 | mean2], 144B pitch
    __shared__ _Float16 Wh[32][72];     // W rows fp16, 144B pitch
    __shared__ _Float16 u16[72];        // user row (renormed)
    __shared__ float mean1p[2][36];     // partial sums of h1 rows (x8 each)
    __shared__ float xe[68];            // [v0 | meanv1]
    __shared__ float bs[32];

    const int user = users[b];
    const int rid0 = rules[r * 2 + 0];
    const int rid1 = rules[r * 2 + 1];

    // longest dependency chain first: hop1 ids (per-wave, no barrier)
    int h1v = 0;
    if (lane < 16) h1v = adj[(rid0 * E_NUMC + user) * NEIGHC + lane];

    // ---- phase B ids: node m, child j ----
    const int m = t >> 4;
    const int j = t & 15;
    const int e1 = __shfl(h1v, m, 64);
    const int e2 = adj[(rid1 * E_NUMC + e1) * NEIGHC + j];

    // ---- phase C loads issued early: 17 rows, 8 B/lane (fp16 table) ----
    const int g = t >> 3, k8 = t & 7;
    const bool cact = (t < 136);
    h2x2 craw;
    if (cact) {
        const int ec = (g < 16) ? __shfl(h1v, g, 64) : user;
        craw = ((const h2x2*)(emb16 + (long)ec * (DIMC / 2)))[k8];
    }

    // ---- stage W as fp16: thread -> (o = t>>3, oct = t&7), 8 floats ----
    {
        const float4* W4 = (const float4*)W;
        const int o = t >> 3, oct = t & 7;
        const float4 wa = W4[o * 16 + 2 * oct];
        const float4 wb = W4[o * 16 + 2 * oct + 1];
        half8 hw;
        hw[0] = (_Float16)wa.x; hw[1] = (_Float16)wa.y;
        hw[2] = (_Float16)wa.z; hw[3] = (_Float16)wa.w;
        hw[4] = (_Float16)wb.x; hw[5] = (_Float16)wb.y;
        hw[6] = (_Float16)wb.z; hw[7] = (_Float16)wb.w;
        *(half8*)&Wh[o][8 * oct] = hw;
    }
    if (t < 32) bs[t] = bvec[t];

    // ---- phase B: fp8 gather (uint2 = 8 dims) + decode + butterfly ----
    {
        const int k = j & 3;        // 8-dim chunk: dims 8k..8k+7 (8 bytes)
        const int h = j >> 2;       // child subset
        const int gbase = t & 48;   // wave-local base lane of this node group
        float acc[8];
#pragma unroll
        for (int d = 0; d < 8; ++d) acc[d] = 0.0f;
#pragma unroll
        for (int i = 0; i < 4; ++i) {
            const int ec = __shfl(e2, gbase + h + 4 * i, 64);
            const uint2 v = emb8[(long)ec * 4 + k];   // row = 4 x uint2
            const fx2 p0 = __builtin_amdgcn_cvt_pk_f32_fp8(v.x, false);
            const fx2 p1 = __builtin_amdgcn_cvt_pk_f32_fp8(v.x, true);
            const fx2 p2 = __builtin_amdgcn_cvt_pk_f32_fp8(v.y, false);
            const fx2 p3 = __builtin_amdgcn_cvt_pk_f32_fp8(v.y, true);
            acc[0] += p0[0]; acc[1] += p0[1];
            acc[2] += p1[0]; acc[3] += p1[1];
            acc[4] += p2[0]; acc[5] += p2[1];
            acc[6] += p3[0]; acc[7] += p3[1];
        }
#pragma unroll
        for (int d = 0; d < 8; ++d) acc[d] += __shfl_xor(acc[d], 4, 64);
#pragma unroll
        for (int d = 0; d < 8; ++d) acc[d] += __shfl_xor(acc[d], 8, 64);
        *(__half2*)&Xh[m][32 + 8 * k + 2 * h] =
            __floats2half2_rn(acc[2 * h] * (1.0f / 16.0f),
                              acc[2 * h + 1] * (1.0f / 16.0f));
    }

    // ---- phase C: store hop1/user rows + mean1 partial reduction ----
    if (cact) {
        if (g < 16) *(h2x2*)&Xh[g][4 * k8] = craw;
        else        *(h2x2*)&u16[4 * k8] = craw;
    }
    if (t < 128) {
        const float2 fa = __half22float2(craw.x);
        const float2 fb = __half22float2(craw.y);
        float c0 = fa.x, c1 = fa.y, c2 = fb.x, c3 = fb.y;
#pragma unroll
        for (int st = 8; st <= 32; st <<= 1) {
            c0 += __shfl_xor(c0, st, 64);
            c1 += __shfl_xor(c1, st, 64);
            c2 += __shfl_xor(c2, st, 64);
            c3 += __shfl_xor(c3, st, 64);
        }
        if ((lane & 56) == 0)   // lane < 8 (= k8)
            *(float4*)&mean1p[wave][4 * k8] = make_float4(c0, c1, c2, c3);
    }
    __syncthreads();   // barrier 1: Xh, u16, Wh, bs, mean1p visible

    const int cn = lane & 15;      // col (out) / row-id within fragments
    const int kg = lane >> 4;      // k-octet group
    if (wave < 2) {
        // ---- phase D: 16 nodes x 16 outs (N-half = wave), K = 64 ----
        const half8 a0 = *(const half8*)&Xh[cn][8 * kg];
        const half8 a1 = *(const half8*)&Xh[cn][32 + 8 * kg];
        const half8 b0 = *(const half8*)&Wh[cn + 16 * wave][8 * kg];
        const half8 b1 = *(const half8*)&Wh[cn + 16 * wave][32 + 8 * kg];
        floatx4 acc = {0.0f, 0.0f, 0.0f, 0.0f};
        acc = __builtin_amdgcn_mfma_f32_16x16x32_f16(a0, b0, acc, 0, 0, 0);
        acc = __builtin_amdgcn_mfma_f32_16x16x32_f16(a1, b1, acc, 0, 0, 0);
        const float bb = bs[cn + 16 * wave];
        float csum = 0.0f;
#pragma unroll
        for (int q = 0; q < 4; ++q) csum += fmaxf(acc[q] + bb, 0.0f);
        csum += __shfl_xor(csum, 16, 64);
        csum += __shfl_xor(csum, 32, 64);
        if (lane < 16) xe[32 + cn + 16 * wave] = csum * (1.0f / 16.0f);
    } else if (wave == 2) {
        // ---- v0 = relu(W [u | mean1] + b), split across d-halves ----
        const int o = lane & 31, h = lane >> 5;
        float a = 0.0f;
        if (h == 0) {
#pragma unroll
            for (int oct = 0; oct < 4; ++oct) {
                const half8 u = *(const half8*)&u16[8 * oct];
                const half8 w = *(const half8*)&Wh[o][8 * oct];
#pragma unroll
                for (int q = 0; q < 8; ++q) a += (float)u[q] * (float)w[q];
            }
        } else {
#pragma unroll
            for (int oct = 0; oct < 4; ++oct) {
                const half8 w = *(const half8*)&Wh[o][32 + 8 * oct];
                const float4 p0a = *(const float4*)&mean1p[0][8 * oct];
                const float4 p0b = *(const float4*)&mean1p[0][8 * oct + 4];
                const float4 p1a = *(const float4*)&mean1p[1][8 * oct];
                const float4 p1b = *(const float4*)&mean1p[1][8 * oct + 4];
                a += (float)w[0] * (p0a.x + p1a.x) + (float)w[1] * (p0a.y + p1a.y)
                   + (float)w[2] * (p0a.z + p1a.z) + (float)w[3] * (p0a.w + p1a.w)
                   + (float)w[4] * (p0b.x + p1b.x) + (float)w[5] * (p0b.y + p1b.y)
                   + (float)w[6] * (p0b.z + p1b.z) + (float)w[7] * (p0b.w + p1b.w);
            }
            a *= (1.0f / 16.0f);   // mean1 partials are sums over 16 rows
        }
        a += __shfl_xor(a, 32, 64);
        if (h == 0) xe[o] = fmaxf(a + bs[o], 0.0f);
    }
    __syncthreads();   // barrier 2: xe ready

    // ---- phase E: wave 0, out o, halves over d ----
    if (t < 64) {
        const int o = lane & 31, h = lane >> 5;
        float a = 0.0f;
#pragma unroll
        for (int oct = 4 * h; oct < 4 * h + 4; ++oct) {
            const half8 w = *(const half8*)&Wh[o][8 * oct];
            const float4 xa = *(const float4*)&xe[8 * oct];
            const float4 xb = *(const float4*)&xe[8 * oct + 4];
            a += (float)w[0] * xa.x + (float)w[1] * xa.y
               + (float)w[2] * xa.z + (float)w[3] * xa.w
               + (float)w[4] * xb.x + (float)w[5] * xb.y
               + (float)w[6] * xb.z + (float)w[7] * xb.w;
        }
        a += __shfl_xor(a, 32, 64);
        if (h == 0)
            res[(b * RULESC + r) * DIMC + o] = tanhf(a + bs[o]);
    }
}

// ---------------------------------------------------------------------------
// Kernel 2: one wave per batch element — rule-weighted sum + item dot+sigmoid
// (item row renormed from the ORIGINAL fp32 table for final accuracy)
// ---------------------------------------------------------------------------
__global__ __launch_bounds__(256) void rgrec_combine_kernel(
    const int* __restrict__ items, const float* __restrict__ emb,
    const float* __restrict__ rule_w, const float* __restrict__ res,
    float* __restrict__ out, int B)
{
    const int gw = (blockIdx.x * 256 + threadIdx.x) >> 6;
    const int lane = threadIdx.x & 63;
    if (gw >= B) return;
    const int b = gw;

    float ss = 0.0f;
#pragma unroll
    for (int i = 0; i < RULESC; ++i) { const float w = rule_w[i]; ss += w * w; }
    const float rws = fminf(1.0f, 1.0f / fmaxf(sqrtf(ss), 1e-7f));

    const int d = lane & 31, rh = lane >> 5;
    float acc = 0.0f;
#pragma unroll
    for (int rr = 0; rr < 4; ++rr) {
        const int r = rh * 4 + rr;
        acc += rule_w[r] * res[(b * RULESC + r) * DIMC + d];
    }
    acc += __shfl_xor(acc, 32, 64);
    acc *= rws;

    const int it = items[b];
    const float x = emb[(long)it * DIMC + d];
    float sq = x * x;
    sq += __shfl_xor(sq, 1, 64);
    sq += __shfl_xor(sq, 2, 64);
    sq += __shfl_xor(sq, 4, 64);
    sq += __shfl_xor(sq, 8, 64);
    sq += __shfl_xor(sq, 16, 64);
    const float s = fminf(1.0f, 1.0f / fmaxf(sqrtf(sq), 1e-7f));
    float p = acc * x * s;
    p += __shfl_xor(p, 1, 64);
    p += __shfl_xor(p, 2, 64);
    p += __shfl_xor(p, 4, 64);
    p += __shfl_xor(p, 8, 64);
    p += __shfl_xor(p, 16, 64);
    if (lane == 0) out[b] = 1.0f / (1.0f + expf(-p));
}

// ---------------------------------------------------------------------------
// Fallback fused fp32 kernel (known-good) if d_ws is too small.
// ---------------------------------------------------------------------------
__global__ __launch_bounds__(256) void rgrec_fused_kernel(
    const int* __restrict__ users, const int* __restrict__ items,
    const int* __restrict__ rules, const int* __restrict__ adj,
    const float* __restrict__ emb, const float* __restrict__ rule_w,
    const float* __restrict__ W, const float* __restrict__ bvec,
    float* __restrict__ out)
{
    const int b = blockIdx.x;
    const int t = threadIdx.x;

    __shared__ float Wt[64][33];
    __shared__ float bs[32];
    __shared__ float h1s[16][33];
    __shared__ float mean2[16][33];
    __shared__ float v1[16][33];
    __shared__ float u_vec[32];
    __shared__ float mean1[32];
    __shared__ float v0[32];
    __shared__ float meanv1[32];
    __shared__ float useru[32];
    __shared__ int   h1id[16];

    for (int i = t; i < 64 * 32; i += 256) {
        const int o = i >> 6, d = i & 63;
        Wt[d][o] = W[i];
    }
    if (t < 32) { bs[t] = bvec[t]; useru[t] = 0.0f; }

    float ss = 0.0f;
#pragma unroll
    for (int i = 0; i < RULESC; ++i) { const float w = rule_w[i]; ss += w * w; }
    const float rws = fminf(1.0f, 1.0f / fmaxf(sqrtf(ss), 1e-7f));

    const int user = users[b];

    for (int r = 0; r < RULESC; ++r) {
        const int rid0 = rules[r * 2 + 0];
        const int rid1 = rules[r * 2 + 1];
        if (t < 16) h1id[t] = adj[(rid0 * E_NUMC + user) * NEIGHC + t];
        __syncthreads();
        {
            const int m = t >> 4, j = t & 15;
            const int e1 = h1id[m];
            const int e2 = adj[(rid1 * E_NUMC + e1) * NEIGHC + j];
            float v[32];
            const float4* p = (const float4*)(emb + (long)e2 * DIMC);
            float sq = 0.0f;
#pragma unroll
            for (int q = 0; q < 8; ++q) {
                const float4 f = p[q];
                v[q * 4 + 0] = f.x; v[q * 4 + 1] = f.y;
                v[q * 4 + 2] = f.z; v[q * 4 + 3] = f.w;
                sq += f.x * f.x + f.y * f.y + f.z * f.z + f.w * f.w;
            }
            const float s =
                fminf(1.0f, 1.0f / fmaxf(sqrtf(sq), 1e-7f)) * (1.0f / 16.0f);
#pragma unroll
            for (int d = 0; d < 32; ++d) v[d] *= s;
#pragma unroll
            for (int st = 1; st < 16; st <<= 1) {
#pragma unroll
                for (int d = 0; d < 32; ++d) v[d] += __shfl_xor(v[d], st, 64);
            }
            mean2[m][j]      = v[j];
            mean2[m][j + 16] = v[j + 16];
        }
        if (t < 136) {
            const int g = t >> 3, k = t & 7;
            const int e = (g < 16) ? h1id[g] : user;
            const float4 f = ((const float4*)(emb + (long)e * DIMC))[k];
            float sq = f.x * f.x + f.y * f.y + f.z * f.z + f.w * f.w;
            sq += __shfl_xor(sq, 1, 64);
            sq += __shfl_xor(sq, 2, 64);
            sq += __shfl_xor(sq, 4, 64);
            const float s = fminf(1.0f, 1.0f / fmaxf(sqrtf(sq), 1e-7f));
            if (g < 16) {
                h1s[g][k * 4 + 0] = f.x * s; h1s[g][k * 4 + 1] = f.y * s;
                h1s[g][k * 4 + 2] = f.z * s; h1s[g][k * 4 + 3] = f.w * s;
            } else {
                u_vec[k * 4 + 0] = f.x * s; u_vec[k * 4 + 1] = f.y * s;
                u_vec[k * 4 + 2] = f.z * s; u_vec[k * 4 + 3] = f.w * s;
            }
        }
        __syncthreads();
        {
            const int m = t >> 4, o = t & 15;
            float a0 = bs[o], a1 = bs[o + 16];
#pragma unroll
            for (int d = 0; d < 32; ++d) {
                const float h = h1s[m][d];
                a0 += Wt[d][o] * h;
                a1 += Wt[d][o + 16] * h;
            }
#pragma unroll
            for (int d = 0; d < 32; ++d) {
                const float h = mean2[m][d];
                a0 += Wt[32 + d][o] * h;
                a1 += Wt[32 + d][o + 16] * h;
            }
            v1[m][o]      = fmaxf(a0, 0.0f);
            v1[m][o + 16] = fmaxf(a1, 0.0f);
        }
        if (t < 32) {
            float mn = 0.0f;
#pragma unroll
            for (int m2 = 0; m2 < 16; ++m2) mn += h1s[m2][t];
            mean1[t] = mn * (1.0f / 16.0f);
        }
        __syncthreads();
        if (t < 32) {
            float a = bs[t];
#pragma unroll
            for (int d = 0; d < 32; ++d) a += Wt[d][t] * u_vec[d];
#pragma unroll
            for (int d = 0; d < 32; ++d) a += Wt[32 + d][t] * mean1[d];
            v0[t] = fmaxf(a, 0.0f);
            float mv = 0.0f;
#pragma unroll
            for (int m2 = 0; m2 < 16; ++m2) mv += v1[m2][t];
            meanv1[t] = mv * (1.0f / 16.0f);
        }
        __syncthreads();
        if (t < 32) {
            float a = bs[t];
#pragma unroll
            for (int d = 0; d < 32; ++d) a += Wt[d][t] * v0[d];
#pragma unroll
            for (int d = 0; d < 32; ++d) a += Wt[32 + d][t] * meanv1[d];
            useru[t] += rule_w[r] * rws * tanhf(a);
        }
        __syncthreads();
    }

    if (t < 32) {
        const int it = items[b];
        const float x = emb[(long)it * DIMC + t];
        float sq = x * x;
        sq += __shfl_xor(sq, 1, 64);
        sq += __shfl_xor(sq, 2, 64);
        sq += __shfl_xor(sq, 4, 64);
        sq += __shfl_xor(sq, 8, 64);
        sq += __shfl_xor(sq, 16, 64);
        const float s = fminf(1.0f, 1.0f / fmaxf(sqrtf(sq), 1e-7f));
        float p = useru[t] * x * s;
        p += __shfl_xor(p, 1, 64);
        p += __shfl_xor(p, 2, 64);
        p += __shfl_xor(p, 4, 64);
        p += __shfl_xor(p, 8, 64);
        p += __shfl_xor(p, 16, 64);
        if (t == 0) out[b] = 1.0f / (1.0f + expf(-p));
    }
}

extern "C" void kernel_launch(void* const* d_in, const int* in_sizes, int n_in,
                              void* d_out, int out_size, void* d_ws, size_t ws_size,
                              hipStream_t stream) {
    const int*   users  = (const int*)d_in[0];
    const int*   items  = (const int*)d_in[1];
    const int*   rules  = (const int*)d_in[2];
    const int*   adj    = (const int*)d_in[3];
    const float* emb    = (const float*)d_in[4];
    const float* rule_w = (const float*)d_in[5];
    const float* W      = (const float*)d_in[6];
    const float* bvec   = (const float*)d_in[7];
    float*       out    = (float*)d_out;

    const int batch = in_sizes[0];  // 1024
    const size_t emb16_bytes = (size_t)E_NUMC * DIMC * sizeof(__half);  // 6.4 MB
    const size_t emb8_bytes  = (size_t)E_NUMC * DIMC;                   // 3.2 MB
    const size_t res_bytes   = (size_t)batch * RULESC * DIMC * sizeof(float);

    if (ws_size >= emb16_bytes + emb8_bytes + res_bytes) {
        __half2* emb16 = (__half2*)d_ws;
        short*   emb8s = (short*)((char*)d_ws + emb16_bytes);
        float*   res   = (float*)((char*)d_ws + emb16_bytes + emb8_bytes);

        renorm_kernel<<<dim3(E_NUMC / 16), dim3(256), 0, stream>>>(
            emb, emb16, emb8s);
        rgrec_tree16_kernel<<<dim3(batch, RULESC), dim3(256), 0, stream>>>(
            users, rules, adj, emb16, (const uint2*)emb8s, W, bvec, res);
        const int nblk = (batch * 64 + 255) / 256;
        rgrec_combine_kernel<<<dim3(nblk), dim3(256), 0, stream>>>(
            items, emb, rule_w, res, out, batch);
    } else {
        rgrec_fused_kernel<<<dim3(batch), dim3(256), 0, stream>>>(
            users, items, rules, adj, emb, rule_w, W, bvec, out);
    }
}